// Round 1
// baseline (2720.198 us; speedup 1.0000x reference)
//
#include <hip/hip_runtime.h>
#include <hip/hip_bf16.h>

// Problem constants (B=2, S=2048, H=4096, V=32000)
#define T_TOK 4096
#define HDIM  4096
#define VOCAB 32000
#define BM 128
#define BN 128
#define BK 64
#define NTT (T_TOK / BM)   // 32 token tiles
#define NVT (VOCAB / BN)   // 250 vocab tiles

typedef float  f32x4  __attribute__((ext_vector_type(4)));
typedef __bf16 bf16x8 __attribute__((ext_vector_type(8)));

// Fused GEMM (logits tile) + online CE epilogue.
// C[t][v] = sum_h hs[t][h] * W[v][h]  -- both operands K-contiguous (NT GEMM).
__global__ __launch_bounds__(256) void ce_fused_gemm_38766374814398(
    const float* __restrict__ hs, const float* __restrict__ wt,
    const int* __restrict__ labels, float* __restrict__ sumexp,
    float* __restrict__ picked)
{
  __shared__ __bf16 lA[BM * BK];   // 16 KB, XOR-swizzled 16B slots
  __shared__ __bf16 lB[BN * BK];   // 16 KB

  const int tid  = threadIdx.x;
  const int lane = tid & 63;
  const int wid  = tid >> 6;
  const int wm   = wid >> 1;       // 2x2 wave grid, each wave owns 64x64
  const int wn   = wid & 1;

  // Bijective XCD swizzle (8000 blocks = 8 XCD * 1000), then vocab-tile-major:
  // consecutive work per XCD shares weight tiles; hidden (67MB) stays LLC-hot.
  const int bid = blockIdx.x;
  const int sw  = (bid & 7) * (NTT * NVT / 8) + (bid >> 3);
  const int vt  = sw >> 5;         // 0..249
  const int tt  = sw & 31;         // 0..31

  const float* gA = hs + (size_t)tt * BM * HDIM;
  const float* gB = wt + (size_t)vt * BN * HDIM;

  f32x4 acc[4][4];
#pragma unroll
  for (int i = 0; i < 4; ++i)
#pragma unroll
    for (int j = 0; j < 4; ++j)
      acc[i][j] = (f32x4){0.f, 0.f, 0.f, 0.f};

  for (int kt = 0; kt < HDIM / BK; ++kt) {
    const int kbase = kt * BK;
    // ---- stage: fp32 global -> cvt -> bf16 LDS (reg-staged, swizzled) ----
#pragma unroll
    for (int t = 0; t < 4; ++t) {
      const int c   = t * 256 + tid;       // chunk id, 8 floats each
      const int row = c >> 3;              // 0..127
      const int kc  = (c & 7) << 3;        // 0,8,..,56
      const float* g = gA + (size_t)row * HDIM + kbase + kc;
      f32x4 p0 = *(const f32x4*)g;
      f32x4 p1 = *(const f32x4*)(g + 4);
      bf16x8 v;
      v[0] = (__bf16)p0[0]; v[1] = (__bf16)p0[1]; v[2] = (__bf16)p0[2]; v[3] = (__bf16)p0[3];
      v[4] = (__bf16)p1[0]; v[5] = (__bf16)p1[1]; v[6] = (__bf16)p1[2]; v[7] = (__bf16)p1[3];
      *(bf16x8*)&lA[(row << 6) + ((((c & 7) ^ row) & 7) << 3)] = v;
    }
#pragma unroll
    for (int t = 0; t < 4; ++t) {
      const int c   = t * 256 + tid;
      const int row = c >> 3;
      const int kc  = (c & 7) << 3;
      const float* g = gB + (size_t)row * HDIM + kbase + kc;
      f32x4 p0 = *(const f32x4*)g;
      f32x4 p1 = *(const f32x4*)(g + 4);
      bf16x8 v;
      v[0] = (__bf16)p0[0]; v[1] = (__bf16)p0[1]; v[2] = (__bf16)p0[2]; v[3] = (__bf16)p0[3];
      v[4] = (__bf16)p1[0]; v[5] = (__bf16)p1[1]; v[6] = (__bf16)p1[2]; v[7] = (__bf16)p1[3];
      *(bf16x8*)&lB[(row << 6) + ((((c & 7) ^ row) & 7) << 3)] = v;
    }
    __syncthreads();

    // ---- compute: 2 k-steps of K=32, 16 MFMA each ----
#pragma unroll
    for (int kk = 0; kk < 2; ++kk) {
      bf16x8 af[4], bfr[4];
      const int slot = kk * 4 + (lane >> 4);
#pragma unroll
      for (int mi = 0; mi < 4; ++mi) {
        const int ar = wm * 64 + mi * 16 + (lane & 15);
        af[mi] = *(const bf16x8*)&lA[(ar << 6) + (((slot ^ ar) & 7) << 3)];
      }
#pragma unroll
      for (int ni = 0; ni < 4; ++ni) {
        const int br = wn * 64 + ni * 16 + (lane & 15);
        bfr[ni] = *(const bf16x8*)&lB[(br << 6) + (((slot ^ br) & 7) << 3)];
      }
#pragma unroll
      for (int mi = 0; mi < 4; ++mi)
#pragma unroll
        for (int ni = 0; ni < 4; ++ni)
          acc[mi][ni] = __builtin_amdgcn_mfma_f32_16x16x32_bf16(af[mi], bfr[ni], acc[mi][ni], 0, 0, 0);
    }
    __syncthreads();
  }

  // ---- CE epilogue on accumulator fragments ----
  // C/D layout (HW-verified): col = lane&15, row = (lane>>4)*4 + reg
  const int row0 = tt * BM + wm * 64 + ((lane >> 4) << 2);
  const int col0 = vt * BN + wn * 64 + (lane & 15);
#pragma unroll
  for (int mi = 0; mi < 4; ++mi) {
#pragma unroll
    for (int r = 0; r < 4; ++r) {
      const int row = row0 + mi * 16 + r;
      const int lab = labels[row];
      float se = 0.f;
#pragma unroll
      for (int ni = 0; ni < 4; ++ni) {
        const float lg = acc[mi][ni][r];
        se += expf(lg);                      // logits bounded ~|8|: no overflow
        if (col0 + ni * 16 == lab) picked[row] = lg;  // exactly one writer/token
      }
      // reduce across the 16 lanes (cols) of this quarter-wave group
      se += __shfl_xor(se, 1, 64);
      se += __shfl_xor(se, 2, 64);
      se += __shfl_xor(se, 4, 64);
      se += __shfl_xor(se, 8, 64);
      if ((lane & 15) == 0) atomicAdd(&sumexp[row], se);
    }
  }
}

__global__ __launch_bounds__(256) void ce_reduce_38766374814398(
    const float* __restrict__ sumexp, const float* __restrict__ picked,
    const float* __restrict__ lw, const int* __restrict__ gas,
    float* __restrict__ out)
{
  __shared__ float sl[4], sww[4];
  const int tid = threadIdx.x;
  float accl = 0.f, accw = 0.f;
  for (int t = tid; t < T_TOK; t += 256) {
    const float w = lw[t];
    accl += w * (logf(sumexp[t]) - picked[t]);
    accw += w;
  }
#pragma unroll
  for (int off = 32; off > 0; off >>= 1) {
    accl += __shfl_down(accl, off, 64);
    accw += __shfl_down(accw, off, 64);
  }
  if ((tid & 63) == 0) { sl[tid >> 6] = accl; sww[tid >> 6] = accw; }
  __syncthreads();
  if (tid == 0) {
    float L = 0.f, W = 0.f;
#pragma unroll
    for (int i = 0; i < 4; ++i) { L += sl[i]; W += sww[i]; }
    out[0] = L / (W + 1e-8f) / (float)gas[0];
  }
}

extern "C" void kernel_launch(void* const* d_in, const int* in_sizes, int n_in,
                              void* d_out, int out_size, void* d_ws, size_t ws_size,
                              hipStream_t stream) {
  const float* hs     = (const float*)d_in[0];   // [B,S,H] fp32
  const float* wt     = (const float*)d_in[1];   // [V,H]   fp32
  const int*   labels = (const int*)d_in[2];     // [B,S]
  const float* lw     = (const float*)d_in[3];   // [B,S]   fp32
  const int*   gas    = (const int*)d_in[4];     // scalar

  float* sumexp = (float*)d_ws;
  float* picked = sumexp + T_TOK;

  hipMemsetAsync(sumexp, 0, T_TOK * sizeof(float), stream);

  ce_fused_gemm_38766374814398<<<dim3(NTT * NVT), dim3(256), 0, stream>>>(
      hs, wt, labels, sumexp, picked);
  ce_reduce_38766374814398<<<dim3(1), dim3(256), 0, stream>>>(
      sumexp, picked, lw, gas, (float*)d_out);
}

// Round 2
// 1932.070 us; speedup vs baseline: 1.4079x; 1.4079x over previous
//
#include <hip/hip_runtime.h>
#include <hip/hip_bf16.h>

// Problem constants (B=2, S=2048, H=4096, V=32000)
#define T_TOK 4096
#define HDIM  4096
#define VOCAB 32000
#define BM 128
#define BN 128
#define BK 64
#define NTT (T_TOK / BM)   // 32 token tiles
#define NVT (VOCAB / BN)   // 250 vocab tiles

typedef float  f32x4  __attribute__((ext_vector_type(4)));
typedef __bf16 bf16x8 __attribute__((ext_vector_type(8)));

// async global->LDS, 16B per lane; LDS dest is wave-uniform base + lane*16
#define GLD_LDS16(gsrc, ldst)                                                  \
  __builtin_amdgcn_global_load_lds(                                            \
      (const __attribute__((address_space(1))) void*)(gsrc),                   \
      (__attribute__((address_space(3))) void*)(ldst), 16, 0, 0)

// ---------------- fp32 -> bf16 conversion (memory-bound pass) ----------------
__global__ __launch_bounds__(256) void ce_cvt_bf16_38766374814398(
    const float* __restrict__ in, __bf16* __restrict__ out, int n)
{
  const int stride = gridDim.x * blockDim.x * 8;
  for (int i = (blockIdx.x * blockDim.x + threadIdx.x) * 8; i < n; i += stride) {
    f32x4 a = *(const f32x4*)(in + i);
    f32x4 b = *(const f32x4*)(in + i + 4);
    bf16x8 v;
    v[0] = (__bf16)a[0]; v[1] = (__bf16)a[1]; v[2] = (__bf16)a[2]; v[3] = (__bf16)a[3];
    v[4] = (__bf16)b[0]; v[5] = (__bf16)b[1]; v[6] = (__bf16)b[2]; v[7] = (__bf16)b[3];
    *(bf16x8*)(out + i) = v;
  }
}

// ------------- bf16 GEMM (m97 structure) + fused CE epilogue -----------------
__global__ __launch_bounds__(256) void ce_gemm_bf16_38766374814398(
    const __bf16* __restrict__ Abf, const __bf16* __restrict__ Wbf,
    const int* __restrict__ labels, float* __restrict__ sumexp,
    float* __restrict__ picked)
{
  __shared__ __bf16 lA[BM * BK];   // 16 KB, linear [row][k]
  __shared__ __bf16 lB[BN * BK];   // 16 KB

  const int tid  = threadIdx.x;
  const int lane = tid & 63;
  const int wid  = tid >> 6;
  const int wm   = wid >> 1;       // 2x2 wave grid, each wave owns 64x64
  const int wn   = wid & 1;

  // Bijective XCD swizzle (8000 = 8 * 1000), vocab-tile-major within XCD:
  // A (33.5 MB bf16) stays L3-resident; each W panel reused by 32 blocks in L2.
  const int bid = blockIdx.x;
  const int sw  = (bid & 7) * (NTT * NVT / 8) + (bid >> 3);
  const int vt  = sw >> 5;         // 0..249
  const int tt  = sw & 31;         // 0..31

  const __bf16* gA = Abf + (size_t)tt * BM * HDIM;
  const __bf16* gB = Wbf + (size_t)vt * BN * HDIM;

  f32x4 acc[4][4];
#pragma unroll
  for (int i = 0; i < 4; ++i)
#pragma unroll
    for (int j = 0; j < 4; ++j)
      acc[i][j] = (f32x4){0.f, 0.f, 0.f, 0.f};

  for (int kt = 0; kt < HDIM / BK; ++kt) {
    const int kbase = kt * BK;
    // ---- stage via global_load_lds width=16: 16 chunks of 1 KB per operand --
    // chunk c covers rows c*8..c*8+7; lane l -> row c*8 + (l>>3), k (l&7)*8
#pragma unroll
    for (int c = 0; c < 4; ++c) {
      const int chunk = wid * 4 + c;
      const int row   = chunk * 8 + (lane >> 3);
      GLD_LDS16(gA + (size_t)row * HDIM + kbase + (lane & 7) * 8, &lA[chunk * 512]);
    }
#pragma unroll
    for (int c = 0; c < 4; ++c) {
      const int chunk = wid * 4 + c;
      const int row   = chunk * 8 + (lane >> 3);
      GLD_LDS16(gB + (size_t)row * HDIM + kbase + (lane & 7) * 8, &lB[chunk * 512]);
    }
    __syncthreads();

    // ---- compute: 2 k-steps of K=32, 16 MFMA each ----
#pragma unroll
    for (int kk = 0; kk < 2; ++kk) {
      bf16x8 af[4], bfr[4];
      const int ko = kk * 32 + (lane >> 4) * 8;
#pragma unroll
      for (int mi = 0; mi < 4; ++mi) {
        const int ar = wm * 64 + mi * 16 + (lane & 15);
        af[mi] = *(const bf16x8*)&lA[ar * BK + ko];
      }
#pragma unroll
      for (int ni = 0; ni < 4; ++ni) {
        const int br = wn * 64 + ni * 16 + (lane & 15);
        bfr[ni] = *(const bf16x8*)&lB[br * BK + ko];
      }
#pragma unroll
      for (int mi = 0; mi < 4; ++mi)
#pragma unroll
        for (int ni = 0; ni < 4; ++ni)
          acc[mi][ni] = __builtin_amdgcn_mfma_f32_16x16x32_bf16(af[mi], bfr[ni], acc[mi][ni], 0, 0, 0);
    }
    __syncthreads();
  }

  // ---- CE epilogue: exp + 16-lane reduce + one atomic per row-group ----
  // C/D layout (HW-verified): col = lane&15, row = (lane>>4)*4 + reg
  const int row0 = tt * BM + wm * 64 + ((lane >> 4) << 2);
  const int col0 = vt * BN + wn * 64 + (lane & 15);
#pragma unroll
  for (int mi = 0; mi < 4; ++mi) {
#pragma unroll
    for (int r = 0; r < 4; ++r) {
      const int row = row0 + mi * 16 + r;
      const int lab = labels[row];
      float se = 0.f;
#pragma unroll
      for (int ni = 0; ni < 4; ++ni) {
        const float lg = acc[mi][ni][r];
        se += expf(lg);                      // logits bounded ~|8|: no overflow
        if (col0 + ni * 16 == lab) picked[row] = lg;  // exactly one writer/token
      }
      se += __shfl_xor(se, 1, 64);
      se += __shfl_xor(se, 2, 64);
      se += __shfl_xor(se, 4, 64);
      se += __shfl_xor(se, 8, 64);
      if ((lane & 15) == 0) atomicAdd(&sumexp[row], se);
    }
  }
}

// ---------------- fallback: round-1 fused fp32->bf16 GEMM --------------------
__global__ __launch_bounds__(256) void ce_fused_gemm_38766374814398(
    const float* __restrict__ hs, const float* __restrict__ wt,
    const int* __restrict__ labels, float* __restrict__ sumexp,
    float* __restrict__ picked)
{
  __shared__ __bf16 lA[BM * BK];
  __shared__ __bf16 lB[BN * BK];

  const int tid  = threadIdx.x;
  const int lane = tid & 63;
  const int wid  = tid >> 6;
  const int wm   = wid >> 1;
  const int wn   = wid & 1;

  const int bid = blockIdx.x;
  const int sw  = (bid & 7) * (NTT * NVT / 8) + (bid >> 3);
  const int vt  = sw >> 5;
  const int tt  = sw & 31;

  const float* gA = hs + (size_t)tt * BM * HDIM;
  const float* gB = wt + (size_t)vt * BN * HDIM;

  f32x4 acc[4][4];
#pragma unroll
  for (int i = 0; i < 4; ++i)
#pragma unroll
    for (int j = 0; j < 4; ++j)
      acc[i][j] = (f32x4){0.f, 0.f, 0.f, 0.f};

  for (int kt = 0; kt < HDIM / BK; ++kt) {
    const int kbase = kt * BK;
#pragma unroll
    for (int t = 0; t < 4; ++t) {
      const int c   = t * 256 + tid;
      const int row = c >> 3;
      const int kc  = (c & 7) << 3;
      const float* g = gA + (size_t)row * HDIM + kbase + kc;
      f32x4 p0 = *(const f32x4*)g;
      f32x4 p1 = *(const f32x4*)(g + 4);
      bf16x8 v;
      v[0] = (__bf16)p0[0]; v[1] = (__bf16)p0[1]; v[2] = (__bf16)p0[2]; v[3] = (__bf16)p0[3];
      v[4] = (__bf16)p1[0]; v[5] = (__bf16)p1[1]; v[6] = (__bf16)p1[2]; v[7] = (__bf16)p1[3];
      *(bf16x8*)&lA[(row << 6) + ((((c & 7) ^ row) & 7) << 3)] = v;
    }
#pragma unroll
    for (int t = 0; t < 4; ++t) {
      const int c   = t * 256 + tid;
      const int row = c >> 3;
      const int kc  = (c & 7) << 3;
      const float* g = gB + (size_t)row * HDIM + kbase + kc;
      f32x4 p0 = *(const f32x4*)g;
      f32x4 p1 = *(const f32x4*)(g + 4);
      bf16x8 v;
      v[0] = (__bf16)p0[0]; v[1] = (__bf16)p0[1]; v[2] = (__bf16)p0[2]; v[3] = (__bf16)p0[3];
      v[4] = (__bf16)p1[0]; v[5] = (__bf16)p1[1]; v[6] = (__bf16)p1[2]; v[7] = (__bf16)p1[3];
      *(bf16x8*)&lB[(row << 6) + ((((c & 7) ^ row) & 7) << 3)] = v;
    }
    __syncthreads();

#pragma unroll
    for (int kk = 0; kk < 2; ++kk) {
      bf16x8 af[4], bfr[4];
      const int slot = kk * 4 + (lane >> 4);
#pragma unroll
      for (int mi = 0; mi < 4; ++mi) {
        const int ar = wm * 64 + mi * 16 + (lane & 15);
        af[mi] = *(const bf16x8*)&lA[(ar << 6) + (((slot ^ ar) & 7) << 3)];
      }
#pragma unroll
      for (int ni = 0; ni < 4; ++ni) {
        const int br = wn * 64 + ni * 16 + (lane & 15);
        bfr[ni] = *(const bf16x8*)&lB[(br << 6) + (((slot ^ br) & 7) << 3)];
      }
#pragma unroll
      for (int mi = 0; mi < 4; ++mi)
#pragma unroll
        for (int ni = 0; ni < 4; ++ni)
          acc[mi][ni] = __builtin_amdgcn_mfma_f32_16x16x32_bf16(af[mi], bfr[ni], acc[mi][ni], 0, 0, 0);
    }
    __syncthreads();
  }

  const int row0 = tt * BM + wm * 64 + ((lane >> 4) << 2);
  const int col0 = vt * BN + wn * 64 + (lane & 15);
#pragma unroll
  for (int mi = 0; mi < 4; ++mi) {
#pragma unroll
    for (int r = 0; r < 4; ++r) {
      const int row = row0 + mi * 16 + r;
      const int lab = labels[row];
      float se = 0.f;
#pragma unroll
      for (int ni = 0; ni < 4; ++ni) {
        const float lg = acc[mi][ni][r];
        se += expf(lg);
        if (col0 + ni * 16 == lab) picked[row] = lg;
      }
      se += __shfl_xor(se, 1, 64);
      se += __shfl_xor(se, 2, 64);
      se += __shfl_xor(se, 4, 64);
      se += __shfl_xor(se, 8, 64);
      if ((lane & 15) == 0) atomicAdd(&sumexp[row], se);
    }
  }
}

// ---------------------------- final reduction --------------------------------
__global__ __launch_bounds__(256) void ce_reduce_38766374814398(
    const float* __restrict__ sumexp, const float* __restrict__ picked,
    const float* __restrict__ lw, const int* __restrict__ gas,
    float* __restrict__ out)
{
  __shared__ float sl[4], sww[4];
  const int tid = threadIdx.x;
  float accl = 0.f, accw = 0.f;
  for (int t = tid; t < T_TOK; t += 256) {
    const float w = lw[t];
    accl += w * (logf(sumexp[t]) - picked[t]);
    accw += w;
  }
#pragma unroll
  for (int off = 32; off > 0; off >>= 1) {
    accl += __shfl_down(accl, off, 64);
    accw += __shfl_down(accw, off, 64);
  }
  if ((tid & 63) == 0) { sl[tid >> 6] = accl; sww[tid >> 6] = accw; }
  __syncthreads();
  if (tid == 0) {
    float L = 0.f, W = 0.f;
#pragma unroll
    for (int i = 0; i < 4; ++i) { L += sl[i]; W += sww[i]; }
    out[0] = L / (W + 1e-8f) / (float)gas[0];
  }
}

extern "C" void kernel_launch(void* const* d_in, const int* in_sizes, int n_in,
                              void* d_out, int out_size, void* d_ws, size_t ws_size,
                              hipStream_t stream) {
  const float* hs     = (const float*)d_in[0];   // [B,S,H] fp32
  const float* wt     = (const float*)d_in[1];   // [V,H]   fp32
  const int*   labels = (const int*)d_in[2];     // [B,S]
  const float* lw     = (const float*)d_in[3];   // [B,S]   fp32
  const int*   gas    = (const int*)d_in[4];     // scalar

  const size_t nA = (size_t)T_TOK * HDIM;        // 16.8M elems
  const size_t nW = (size_t)VOCAB * HDIM;        // 131M elems
  const size_t need = 32768 + (nA + nW) * sizeof(__bf16);

  float* sumexp = (float*)d_ws;
  float* picked = sumexp + T_TOK;

  hipMemsetAsync(sumexp, 0, T_TOK * sizeof(float), stream);

  if (ws_size >= need) {
    __bf16* Abf = (__bf16*)((char*)d_ws + 32768);
    __bf16* Wbf = Abf + nA;
    ce_cvt_bf16_38766374814398<<<dim3(1024), dim3(256), 0, stream>>>(hs, Abf, (int)nA);
    ce_cvt_bf16_38766374814398<<<dim3(2048), dim3(256), 0, stream>>>(wt, Wbf, (int)nW);
    ce_gemm_bf16_38766374814398<<<dim3(NTT * NVT), dim3(256), 0, stream>>>(
        Abf, Wbf, labels, sumexp, picked);
  } else {
    ce_fused_gemm_38766374814398<<<dim3(NTT * NVT), dim3(256), 0, stream>>>(
        hs, wt, labels, sumexp, picked);
  }
  ce_reduce_38766374814398<<<dim3(1), dim3(256), 0, stream>>>(
      sumexp, picked, lw, gas, (float*)d_out);
}

// Round 3
// 1628.955 us; speedup vs baseline: 1.6699x; 1.1861x over previous
//
#include <hip/hip_runtime.h>
#include <hip/hip_bf16.h>

// Problem constants (B=2, S=2048, H=4096, V=32000)
#define T_TOK 4096
#define HDIM  4096
#define VOCAB 32000
#define BM 128
#define BN 128
#define BK 64
#define NTT (T_TOK / BM)   // 32 token tiles
#define NVT (VOCAB / BN)   // 250 vocab tiles

typedef float  f32x4  __attribute__((ext_vector_type(4)));
typedef __bf16 bf16x8 __attribute__((ext_vector_type(8)));

// async global->LDS, 16B per lane; LDS dest is wave-uniform base + lane*16
#define GLD_LDS16(gsrc, ldst)                                                  \
  __builtin_amdgcn_global_load_lds(                                            \
      (const __attribute__((address_space(1))) void*)(gsrc),                   \
      (__attribute__((address_space(3))) void*)(ldst), 16, 0, 0)

// ---------------- fp32 -> bf16 conversion (memory-bound pass) ----------------
__global__ __launch_bounds__(256) void ce_cvt_bf16_38766374814398(
    const float* __restrict__ in, __bf16* __restrict__ out, int n)
{
  const int stride = gridDim.x * blockDim.x * 8;
  for (int i = (blockIdx.x * blockDim.x + threadIdx.x) * 8; i < n; i += stride) {
    f32x4 a = *(const f32x4*)(in + i);
    f32x4 b = *(const f32x4*)(in + i + 4);
    bf16x8 v;
    v[0] = (__bf16)a[0]; v[1] = (__bf16)a[1]; v[2] = (__bf16)a[2]; v[3] = (__bf16)a[3];
    v[4] = (__bf16)b[0]; v[5] = (__bf16)b[1]; v[6] = (__bf16)b[2]; v[7] = (__bf16)b[3];
    *(bf16x8*)(out + i) = v;
  }
}

// ------------- bf16 GEMM (m97 structure + XOR swizzle) + CE epilogue ---------
// LDS content: LDS[p] = logical[swz(p)], swz(p) = p XOR ((row(p)&7)<<4) bytes.
// Achieved per rule #21: linear global_load_lds dest + pre-swizzled global
// source (involution) + swizzled fragment read. Fragment read then spans 8
// distinct 16B slots per 16-lane group -> 2-way conflict (free, m136).
__global__ __launch_bounds__(256) void ce_gemm_bf16_38766374814398(
    const __bf16* __restrict__ Abf, const __bf16* __restrict__ Wbf,
    const int* __restrict__ labels, float* __restrict__ sumexp,
    float* __restrict__ picked)
{
  __shared__ __bf16 lA[BM * BK];   // 16 KB
  __shared__ __bf16 lB[BN * BK];   // 16 KB

  const int tid  = threadIdx.x;
  const int lane = tid & 63;
  const int wid  = tid >> 6;
  const int wm   = wid >> 1;       // 2x2 wave grid, each wave owns 64x64
  const int wn   = wid & 1;

  // XCD-chunked tt-major order: 8000 blocks = 8 XCDs x 1000. Each XCD owns
  // 4 token tiles x all 250 vocab tiles (vt-major inside): A working set
  // 4 MB/XCD (L2/L3-hit); all XCDs stream W's vt panels temporally aligned
  // -> each 1 MB W panel HBM-fetched ~once, L3-served for the other XCDs.
  const int bid = blockIdx.x;
  const int x   = bid & 7;         // nominal XCD
  const int j   = bid >> 3;        // 0..999
  const int tt  = x * 4 + (j & 3); // 0..31
  const int vt  = j >> 2;          // 0..249

  const __bf16* gA = Abf + (size_t)tt * BM * HDIM;
  const __bf16* gB = Wbf + (size_t)vt * BN * HDIM;

  // per-lane pre-swizzled source k-offset (elems): ((l&7)^(l>>3))*8
  const int ksw = (((lane & 7) ^ (lane >> 3)) << 3);

  f32x4 acc[4][4];
#pragma unroll
  for (int i = 0; i < 4; ++i)
#pragma unroll
    for (int j2 = 0; j2 < 4; ++j2)
      acc[i][j2] = (f32x4){0.f, 0.f, 0.f, 0.f};

  for (int kt = 0; kt < HDIM / BK; ++kt) {
    const int kbase = kt * BK;
    // ---- stage via global_load_lds width=16, source pre-swizzled ----
    // chunk c: rows c*8..c*8+7; lane l -> row c*8 + (l>>3), src k = ksw
#pragma unroll
    for (int c = 0; c < 4; ++c) {
      const int chunk = wid * 4 + c;
      const int row   = chunk * 8 + (lane >> 3);
      GLD_LDS16(gA + (size_t)row * HDIM + kbase + ksw, &lA[chunk * 512]);
    }
#pragma unroll
    for (int c = 0; c < 4; ++c) {
      const int chunk = wid * 4 + c;
      const int row   = chunk * 8 + (lane >> 3);
      GLD_LDS16(gB + (size_t)row * HDIM + kbase + ksw, &lB[chunk * 512]);
    }
    __syncthreads();

    // ---- compute: 2 k-steps of K=32, 16 MFMA each; swizzled reads ----
#pragma unroll
    for (int kk = 0; kk < 2; ++kk) {
      bf16x8 af[4], bfr[4];
      const int ko = kk * 32 + (lane >> 4) * 8;
#pragma unroll
      for (int mi = 0; mi < 4; ++mi) {
        const int ar = wm * 64 + mi * 16 + (lane & 15);
        af[mi] = *(const bf16x8*)&lA[ar * BK + (ko ^ ((ar & 7) << 3))];
      }
#pragma unroll
      for (int ni = 0; ni < 4; ++ni) {
        const int br = wn * 64 + ni * 16 + (lane & 15);
        bfr[ni] = *(const bf16x8*)&lB[br * BK + (ko ^ ((br & 7) << 3))];
      }
#pragma unroll
      for (int mi = 0; mi < 4; ++mi)
#pragma unroll
        for (int ni = 0; ni < 4; ++ni)
          acc[mi][ni] = __builtin_amdgcn_mfma_f32_16x16x32_bf16(af[mi], bfr[ni], acc[mi][ni], 0, 0, 0);
    }
    __syncthreads();
  }

  // ---- CE epilogue: exp + 16-lane reduce + one atomic per row-group ----
  // C/D layout (HW-verified): col = lane&15, row = (lane>>4)*4 + reg
  const int row0 = tt * BM + wm * 64 + ((lane >> 4) << 2);
  const int col0 = vt * BN + wn * 64 + (lane & 15);
#pragma unroll
  for (int mi = 0; mi < 4; ++mi) {
#pragma unroll
    for (int r = 0; r < 4; ++r) {
      const int row = row0 + mi * 16 + r;
      const int lab = labels[row];
      float se = 0.f;
#pragma unroll
      for (int ni = 0; ni < 4; ++ni) {
        const float lg = acc[mi][ni][r];
        se += expf(lg);                      // logits bounded ~|8|: no overflow
        if (col0 + ni * 16 == lab) picked[row] = lg;  // exactly one writer/token
      }
      se += __shfl_xor(se, 1, 64);
      se += __shfl_xor(se, 2, 64);
      se += __shfl_xor(se, 4, 64);
      se += __shfl_xor(se, 8, 64);
      if ((lane & 15) == 0) atomicAdd(&sumexp[row], se);
    }
  }
}

// ---------------- fallback: round-1 fused fp32->bf16 GEMM --------------------
__global__ __launch_bounds__(256) void ce_fused_gemm_38766374814398(
    const float* __restrict__ hs, const float* __restrict__ wt,
    const int* __restrict__ labels, float* __restrict__ sumexp,
    float* __restrict__ picked)
{
  __shared__ __bf16 lA[BM * BK];
  __shared__ __bf16 lB[BN * BK];

  const int tid  = threadIdx.x;
  const int lane = tid & 63;
  const int wid  = tid >> 6;
  const int wm   = wid >> 1;
  const int wn   = wid & 1;

  const int bid = blockIdx.x;
  const int sw  = (bid & 7) * (NTT * NVT / 8) + (bid >> 3);
  const int vt  = sw >> 5;
  const int tt  = sw & 31;

  const float* gA = hs + (size_t)tt * BM * HDIM;
  const float* gB = wt + (size_t)vt * BN * HDIM;

  f32x4 acc[4][4];
#pragma unroll
  for (int i = 0; i < 4; ++i)
#pragma unroll
    for (int j = 0; j < 4; ++j)
      acc[i][j] = (f32x4){0.f, 0.f, 0.f, 0.f};

  for (int kt = 0; kt < HDIM / BK; ++kt) {
    const int kbase = kt * BK;
#pragma unroll
    for (int t = 0; t < 4; ++t) {
      const int c   = t * 256 + tid;
      const int row = c >> 3;
      const int kc  = (c & 7) << 3;
      const float* g = gA + (size_t)row * HDIM + kbase + kc;
      f32x4 p0 = *(const f32x4*)g;
      f32x4 p1 = *(const f32x4*)(g + 4);
      bf16x8 v;
      v[0] = (__bf16)p0[0]; v[1] = (__bf16)p0[1]; v[2] = (__bf16)p0[2]; v[3] = (__bf16)p0[3];
      v[4] = (__bf16)p1[0]; v[5] = (__bf16)p1[1]; v[6] = (__bf16)p1[2]; v[7] = (__bf16)p1[3];
      *(bf16x8*)&lA[(row << 6) + ((((c & 7) ^ row) & 7) << 3)] = v;
    }
#pragma unroll
    for (int t = 0; t < 4; ++t) {
      const int c   = t * 256 + tid;
      const int row = c >> 3;
      const int kc  = (c & 7) << 3;
      const float* g = gB + (size_t)row * HDIM + kbase + kc;
      f32x4 p0 = *(const f32x4*)g;
      f32x4 p1 = *(const f32x4*)(g + 4);
      bf16x8 v;
      v[0] = (__bf16)p0[0]; v[1] = (__bf16)p0[1]; v[2] = (__bf16)p0[2]; v[3] = (__bf16)p0[3];
      v[4] = (__bf16)p1[0]; v[5] = (__bf16)p1[1]; v[6] = (__bf16)p1[2]; v[7] = (__bf16)p1[3];
      *(bf16x8*)&lB[(row << 6) + ((((c & 7) ^ row) & 7) << 3)] = v;
    }
    __syncthreads();

#pragma unroll
    for (int kk = 0; kk < 2; ++kk) {
      bf16x8 af[4], bfr[4];
      const int slot = kk * 4 + (lane >> 4);
#pragma unroll
      for (int mi = 0; mi < 4; ++mi) {
        const int ar = wm * 64 + mi * 16 + (lane & 15);
        af[mi] = *(const bf16x8*)&lA[(ar << 6) + (((slot ^ ar) & 7) << 3)];
      }
#pragma unroll
      for (int ni = 0; ni < 4; ++ni) {
        const int br = wn * 64 + ni * 16 + (lane & 15);
        bfr[ni] = *(const bf16x8*)&lB[(br << 6) + (((slot ^ br) & 7) << 3)];
      }
#pragma unroll
      for (int mi = 0; mi < 4; ++mi)
#pragma unroll
        for (int ni = 0; ni < 4; ++ni)
          acc[mi][ni] = __builtin_amdgcn_mfma_f32_16x16x32_bf16(af[mi], bfr[ni], acc[mi][ni], 0, 0, 0);
    }
    __syncthreads();
  }

  const int row0 = tt * BM + wm * 64 + ((lane >> 4) << 2);
  const int col0 = vt * BN + wn * 64 + (lane & 15);
#pragma unroll
  for (int mi = 0; mi < 4; ++mi) {
#pragma unroll
    for (int r = 0; r < 4; ++r) {
      const int row = row0 + mi * 16 + r;
      const int lab = labels[row];
      float se = 0.f;
#pragma unroll
      for (int ni = 0; ni < 4; ++ni) {
        const float lg = acc[mi][ni][r];
        se += expf(lg);
        if (col0 + ni * 16 == lab) picked[row] = lg;
      }
      se += __shfl_xor(se, 1, 64);
      se += __shfl_xor(se, 2, 64);
      se += __shfl_xor(se, 4, 64);
      se += __shfl_xor(se, 8, 64);
      if ((lane & 15) == 0) atomicAdd(&sumexp[row], se);
    }
  }
}

// ---------------------------- final reduction --------------------------------
__global__ __launch_bounds__(256) void ce_reduce_38766374814398(
    const float* __restrict__ sumexp, const float* __restrict__ picked,
    const float* __restrict__ lw, const int* __restrict__ gas,
    float* __restrict__ out)
{
  __shared__ float sl[4], sww[4];
  const int tid = threadIdx.x;
  float accl = 0.f, accw = 0.f;
  for (int t = tid; t < T_TOK; t += 256) {
    const float w = lw[t];
    accl += w * (logf(sumexp[t]) - picked[t]);
    accw += w;
  }
#pragma unroll
  for (int off = 32; off > 0; off >>= 1) {
    accl += __shfl_down(accl, off, 64);
    accw += __shfl_down(accw, off, 64);
  }
  if ((tid & 63) == 0) { sl[tid >> 6] = accl; sww[tid >> 6] = accw; }
  __syncthreads();
  if (tid == 0) {
    float L = 0.f, W = 0.f;
#pragma unroll
    for (int i = 0; i < 4; ++i) { L += sl[i]; W += sww[i]; }
    out[0] = L / (W + 1e-8f) / (float)gas[0];
  }
}

extern "C" void kernel_launch(void* const* d_in, const int* in_sizes, int n_in,
                              void* d_out, int out_size, void* d_ws, size_t ws_size,
                              hipStream_t stream) {
  const float* hs     = (const float*)d_in[0];   // [B,S,H] fp32
  const float* wt     = (const float*)d_in[1];   // [V,H]   fp32
  const int*   labels = (const int*)d_in[2];     // [B,S]
  const float* lw     = (const float*)d_in[3];   // [B,S]   fp32
  const int*   gas    = (const int*)d_in[4];     // scalar

  const size_t nA = (size_t)T_TOK * HDIM;        // 16.8M elems
  const size_t nW = (size_t)VOCAB * HDIM;        // 131M elems
  const size_t need = 32768 + (nA + nW) * sizeof(__bf16);

  float* sumexp = (float*)d_ws;
  float* picked = sumexp + T_TOK;

  hipMemsetAsync(sumexp, 0, T_TOK * sizeof(float), stream);

  if (ws_size >= need) {
    __bf16* Abf = (__bf16*)((char*)d_ws + 32768);
    __bf16* Wbf = Abf + nA;
    ce_cvt_bf16_38766374814398<<<dim3(1024), dim3(256), 0, stream>>>(hs, Abf, (int)nA);
    ce_cvt_bf16_38766374814398<<<dim3(2048), dim3(256), 0, stream>>>(wt, Wbf, (int)nW);
    ce_gemm_bf16_38766374814398<<<dim3(NTT * NVT), dim3(256), 0, stream>>>(
        Abf, Wbf, labels, sumexp, picked);
  } else {
    ce_fused_gemm_38766374814398<<<dim3(NTT * NVT), dim3(256), 0, stream>>>(
        hs, wt, labels, sumexp, picked);
  }
  ce_reduce_38766374814398<<<dim3(1), dim3(256), 0, stream>>>(
      sumexp, picked, lw, gas, (float*)d_out);
}